// Round 7
// baseline (153.368 us; speedup 1.0000x reference)
//
#include <hip/hip_runtime.h>
#include <stdint.h>

typedef unsigned int u32;

using i32x8 = __attribute__((ext_vector_type(8))) int;
using f32x4 = __attribute__((ext_vector_type(4))) float;

#define NROWS 32768   // B*H*W*D / 256 rows after reshape(-1,256)
#define NDIM  256
#define KCODES 8192
#define ND_TOT 8388608
#define CBSCALE 8192.0f   // lifts codebook (+-1.2e-4) into e4m3 range; argmax invariant

// ---------------- prep: cb -> fp8, repacked MFMA-fragment-contiguous ----------------
// Output unit u (16 bytes) <-> (T, kh, s, lane), byte addr = u*16 with
//   T = u>>8 (16-code tile), kh = (u>>7)&1 (K-half), s = (u>>6)&1, lane = u&63.
// Source floats: code = T*16 + (lane&15);
//   off = code*256 + kh*128 + (lane>>4)*32 + s*16   (16 consecutive floats).
// Exactly the per-lane B-fragment byte order of mfma_scale_f32_16x16x128_f8f6f4,
// so the runtime kernel's loads are wave-contiguous 1KB dwordx4 bursts.
__global__ __launch_bounds__(256) void prep_cb8_kernel(const float* __restrict__ cb,
                                                       u32* __restrict__ cbb8,
                                                       float* __restrict__ loss) {
    if (blockIdx.x == 0 && threadIdx.x == 0) loss[0] = 0.f;   // out re-poisoned each call
    int u = blockIdx.x * 256 + threadIdx.x;                   // 0..131071
    int T = u >> 8, rest = u & 255;
    int kh = rest >> 7, s = (rest >> 6) & 1, lane = rest & 63;
    int code = T * 16 + (lane & 15);
    const float* src = cb + (size_t)code * NDIM + kh * 128 + (lane >> 4) * 32 + s * 16;
    uint4 o;
    #pragma unroll
    for (int q = 0; q < 4; q++) {
        float4 v = *(const float4*)(src + q * 4);
        int r = __builtin_amdgcn_cvt_pk_fp8_f32(v.x * CBSCALE, v.y * CBSCALE, 0, false);
        r     = __builtin_amdgcn_cvt_pk_fp8_f32(v.z * CBSCALE, v.w * CBSCALE, r, true);
        ((u32*)&o)[q] = (u32)r;
    }
    *(uint4*)((char*)cbb8 + (size_t)u * 16) = o;
}

// ---------------- fully fused: GEMM + argmax + gather + ST + loss ----------------
// Block = 64 m-rows x ALL 8192 codes; grid 512 = 2 blocks/CU. Each of the 4
// waves holds ALL 64 rows in registers (A replicated) and owns a private
// codebook QUARTER (2048 codes = 128 16-code tiles) streamed from L2.
//
// R7 = R6's ISA-forced 4-buffer register pipeline + LAG-1 ARGMAX.
// R6 measured 777 cyc/SIMD per tile-proc vs the 276-cyc MFMA floor, with
// MfmaUtil 35.7% + VALUBusy 28% (~64% combined, neither pipe full): the
// per-wave order [8 MFMA -> argmax VALU dependent on the 8th MFMA] made
// each wave ping-pong between matrix and VALU phases, and with 2 waves/SIMD
// on the same vmcnt cadence the pipes were never co-fed. Fix: TWO acc sets;
// each phase issues MFMAs for tile t into acc(t&1) then the argmax for tile
// t-1 from the OTHER set (data long ready -> no latency stall; scheduler
// interleaves the VALU under the matrix-pipe occupancy). Parity is
// compile-time in the unrolled bodies (rule #20: static indexing only).
// Load pipeline unchanged from R6: asm global_load_dwordx4 x4 with "=&v"
// early-clobber outputs (plain "=v" let the allocator overlap async load
// dests with the address pair -> runtime fault), vmcnt(12) steady waits +
// sched_barrier(0) fences (rule #18), peeled descending-wait tail,
// zero dead loads.
//
// acc-init eliminated via bias-C on the kh=0 MFMA (+2048 => scores positive
// => float order == int order). Packed-key argmax: 2 VALU/element. After the
// loop: merge 4 quarter-keys in LDS (1KB), gather fp32 codebook rows,
// straight-through write + one atomicAdd loss partial.
__global__ __launch_bounds__(256, 2) void vq_fused_kernel(const float* __restrict__ z,
                                                          const float* __restrict__ cb,
                                                          const u32* __restrict__ cbb8,
                                                          float* __restrict__ out) {
    __shared__ u32 keys_lds[4][64];                  // [wave/quarter][row]
    __shared__ float red[4];

    int m0  = blockIdx.x * 64;
    int tid = threadIdx.x;
    int lane = tid & 63, w = tid >> 6;
    int qbase = w * (KCODES / 4);
    int l15 = lane & 15, quad = lane >> 4;

    // ---- A prologue: ALL 64 block rows x 256 K fp32 -> fp8 in 64 VGPRs ----
    i32x8 A8[2][4];              // [kh(128-wide)][i-frag(16 rows)]
    #pragma unroll
    for (int kh = 0; kh < 2; kh++)
        #pragma unroll
        for (int i = 0; i < 4; i++) {
            const float* p = z + (size_t)(m0 + i * 16 + l15) * NDIM + kh * 128 + quad * 32;
            union { u32 u[8]; i32x8 v; } c;
            #pragma unroll
            for (int g = 0; g < 4; g++) {
                float4 x = *(const float4*)(p + g * 8);
                float4 y = *(const float4*)(p + g * 8 + 4);
                int r = __builtin_amdgcn_cvt_pk_fp8_f32(x.x, x.y, 0, false);
                r     = __builtin_amdgcn_cvt_pk_fp8_f32(x.z, x.w, r, true);
                c.u[g * 2] = (u32)r;
                r = __builtin_amdgcn_cvt_pk_fp8_f32(y.x, y.y, 0, false);
                r = __builtin_amdgcn_cvt_pk_fp8_f32(y.z, y.w, r, true);
                c.u[g * 2 + 1] = (u32)r;
            }
            A8[kh][i] = c.v;
        }
    // drain prologue loads so the raw vmcnt(N) below counts ONLY B-tile loads
    __asm__ volatile("s_waitcnt vmcnt(0)" ::: "memory");
    __builtin_amdgcn_sched_barrier(0);

    // ---- B stream: packed fragment layout, per-lane base + tile offsets ----
    // tile n of wave w lives at bytes (w*128 + n)*4096; lane slice = +lane*16.
    // pieces (kh,s) at byte offsets +0 / +1024 / +2048 / +3072.
    const char* lp = (const char*)cbb8 + (size_t)(w * 128) * 4096 + (size_t)lane * 16;

    auto loadt = [&](int4* b, int n) {
        const char* pa = lp + (size_t)n * 4096;
        asm volatile("global_load_dwordx4 %0, %4, off\n\t"
                     "global_load_dwordx4 %1, %4, off offset:1024\n\t"
                     "global_load_dwordx4 %2, %4, off offset:2048\n\t"
                     "global_load_dwordx4 %3, %4, off offset:3072"
                     : "=&v"(b[0]), "=&v"(b[1]), "=&v"(b[2]), "=&v"(b[3])
                     : "v"(pa));
    };
    // buffer-resident waits; sched_barrier stops consumers hoisting (rule #18)
    auto wait12 = [&]() { asm volatile("s_waitcnt vmcnt(12)" ::: "memory");
                          __builtin_amdgcn_sched_barrier(0); };
    auto wait8  = [&]() { asm volatile("s_waitcnt vmcnt(8)"  ::: "memory");
                          __builtin_amdgcn_sched_barrier(0); };
    auto wait4  = [&]() { asm volatile("s_waitcnt vmcnt(4)"  ::: "memory");
                          __builtin_amdgcn_sched_barrier(0); };
    auto wait0  = [&]() { asm volatile("s_waitcnt vmcnt(0)"  ::: "memory");
                          __builtin_amdgcn_sched_barrier(0); };

    const f32x4 bias4 = {2048.f, 2048.f, 2048.f, 2048.f};
    float mkey[16];
    #pragma unroll
    for (int s = 0; s < 16; s++) mkey[s] = 0.f;

    // MFMA for one 16-code tile into the given acc set (no argmax here)
    auto domfma = [&](f32x4* acc, const int4* b) {
        union { int4 q[2]; i32x8 v; } u0, u1;
        u0.q[0] = b[0]; u0.q[1] = b[1];      // kh=0 fragment (32B/lane)
        u1.q[0] = b[2]; u1.q[1] = b[3];      // kh=1 fragment
        #pragma unroll
        for (int i = 0; i < 4; i++)
            acc[i] = __builtin_amdgcn_mfma_scale_f32_16x16x128_f8f6f4(
                         A8[0][i], u0.v, bias4, 0, 0, 0, 0x7F7F7F7F, 0, 0x7F7F7F7F);
        #pragma unroll
        for (int i = 0; i < 4; i++)
            acc[i] = __builtin_amdgcn_mfma_scale_f32_16x16x128_f8f6f4(
                         A8[1][i], u1.v, acc[i], 0, 0, 0, 0x7F7F7F7F, 0, 0x7F7F7F7F);
    };
    // packed-key argmax for a PREVIOUS tile (data ready a full phase ago)
    auto amax = [&](const f32x4* acc, int n) {
        int cb0 = qbase + n * 16 + l15;
        #pragma unroll
        for (int i = 0; i < 4; i++)
            #pragma unroll
            for (int r = 0; r < 4; r++) {
                u32 p = (__float_as_uint(acc[i][r]) & 0xFFFFE000u) | (u32)cb0;
                mkey[i * 4 + r] = fmaxf(mkey[i * 4 + r], __uint_as_float(p));
            }
    };

    // ---- main loop: 128 tiles, 4 forced reg buffers, 3-deep prefetch,
    //      lag-1 argmax on two acc sets (even tile -> accA, odd -> accB) ----
    f32x4 accA[4], accB[4];
    int4 bb0[4], bb1[4], bb2[4], bb3[4];
    loadt(bb0, 0); loadt(bb1, 1); loadt(bb2, 2);   // prime: 12 loads in flight

    // peeled first group: tiles 0..3 (tile 0 has no lag-1 argmax)
    loadt(bb3, 3);  wait12();  domfma(accA, bb0);
    loadt(bb0, 4);  wait12();  domfma(accB, bb1);  amax(accA, 0);
    loadt(bb1, 5);  wait12();  domfma(accA, bb2);  amax(accB, 1);
    loadt(bb2, 6);  wait12();  domfma(accB, bb3);  amax(accA, 2);

    #pragma unroll 1
    for (int n = 4; n < 124; n += 4) {
        loadt(bb3, n + 3);  wait12();  domfma(accA, bb0);  amax(accB, n - 1);
        loadt(bb0, n + 4);  wait12();  domfma(accB, bb1);  amax(accA, n);
        loadt(bb1, n + 5);  wait12();  domfma(accA, bb2);  amax(accB, n + 1);
        loadt(bb2, n + 6);  wait12();  domfma(accB, bb3);  amax(accA, n + 2);
    }
    // ---- peeled tail: tiles 124..127, descending waits, zero dead loads ----
    loadt(bb3, 127);
    wait12();  domfma(accA, bb0);  amax(accB, 123);
    wait8();   domfma(accB, bb1);  amax(accA, 124);
    wait4();   domfma(accA, bb2);  amax(accB, 125);
    wait0();   domfma(accB, bb3);  amax(accA, 126);
    amax(accB, 127);

    // ---- merge: reduce over 16 col-lanes, stash per-row keys in LDS ----
    #pragma unroll
    for (int s = 0; s < 16; s++) {
        float v = mkey[s];
        #pragma unroll
        for (int sh = 1; sh < 16; sh <<= 1)
            v = fmaxf(v, __shfl_xor(v, sh, 64));
        if (l15 == s)    // one writer per 16-lane group (4 quads -> 4 rows)
            keys_lds[w][(s >> 2) * 16 + quad * 4 + (s & 3)] = __float_as_uint(v);
    }
    __syncthreads();

    // ---- fused gather + straight-through + loss (block's own 64 rows) ----
    int d = lane * 4;
    float sacc = 0.f;
    #pragma unroll
    for (int g = 0; g < 16; g++) {
        int rl = w * 16 + g;
        u32 k0 = keys_lds[0][rl], k1 = keys_lds[1][rl];
        u32 k2 = keys_lds[2][rl], k3 = keys_lds[3][rl];
        u32 a = k0 > k1 ? k0 : k1;
        u32 b = k2 > k3 ? k2 : k3;
        u32 idx = (a > b ? a : b) & 0x1FFFu;
        size_t zoff = (size_t)(m0 + rl) * NDIM + d;
        float4 zv = *(const float4*)(z + zoff);
        float4 qv = *(const float4*)(cb + (size_t)idx * NDIM + d);
        float4 o;
        o.x = zv.x + (qv.x - zv.x);           // straight-through, matches ref fp ops
        o.y = zv.y + (qv.y - zv.y);
        o.z = zv.z + (qv.z - zv.z);
        o.w = zv.w + (qv.w - zv.w);
        *(float4*)(out + zoff) = o;
        float dx = zv.x - qv.x, dy = zv.y - qv.y, dz = zv.z - qv.z, dw = zv.w - qv.w;
        sacc += dx * dx + dy * dy + dz * dz + dw * dw;
    }
    #pragma unroll
    for (int off = 32; off > 0; off >>= 1) sacc += __shfl_down(sacc, off, 64);
    if (lane == 0) red[w] = sacc;
    __syncthreads();
    if (tid == 0) {
        float tot = (red[0] + red[1]) + (red[2] + red[3]);
        atomicAdd(out + ND_TOT, tot * (1.25f / 8388608.f));   // (0.25+1.0)*mean
    }
}

extern "C" void kernel_launch(void* const* d_in, const int* in_sizes, int n_in,
                              void* d_out, int out_size, void* d_ws, size_t ws_size,
                              hipStream_t stream) {
    const float* z  = (const float*)d_in[0];   // 8*256*64*64 fp32
    const float* cb = (const float*)d_in[1];   // 8192*256 fp32
    float* out = (float*)d_out;                // 8388608 quantized_st + 1 loss

    u32* cbb8 = (u32*)d_ws;                    // 2 MB (cb fp8, fragment-packed)

    prep_cb8_kernel<<<KCODES * NDIM / 16 / 256, 256, 0, stream>>>(cb, cbb8, out + ND_TOT);
    vq_fused_kernel<<<NROWS / 64, 256, 0, stream>>>(z, cb, cbb8, out);
}

// Round 8
// 149.484 us; speedup vs baseline: 1.0260x; 1.0260x over previous
//
#include <hip/hip_runtime.h>
#include <stdint.h>

typedef unsigned int u32;

using i32x8 = __attribute__((ext_vector_type(8))) int;
using f32x4 = __attribute__((ext_vector_type(4))) float;

#define NROWS 32768   // B*H*W*D / 256 rows after reshape(-1,256)
#define NDIM  256
#define KCODES 8192
#define ND_TOT 8388608
#define CBSCALE 8192.0f   // lifts codebook (+-1.2e-4) into e4m3 range; argmax invariant

// ---------------- prep: cb -> fp8, repacked MFMA-fragment-contiguous ----------------
// Output unit u (16 bytes) <-> (T, kh, s, lane), byte addr = u*16 with
//   T = u>>8 (16-code tile), kh = (u>>7)&1 (K-half), s = (u>>6)&1, lane = u&63.
// Source floats: code = T*16 + (lane&15);
//   off = code*256 + kh*128 + (lane>>4)*32 + s*16   (16 consecutive floats).
// Exactly the per-lane B-fragment byte order of mfma_scale_f32_16x16x128_f8f6f4,
// so the runtime kernel's loads are wave-contiguous 1KB dwordx4 bursts.
__global__ __launch_bounds__(256) void prep_cb8_kernel(const float* __restrict__ cb,
                                                       u32* __restrict__ cbb8,
                                                       float* __restrict__ loss) {
    if (blockIdx.x == 0 && threadIdx.x == 0) loss[0] = 0.f;   // out re-poisoned each call
    int u = blockIdx.x * 256 + threadIdx.x;                   // 0..131071
    int T = u >> 8, rest = u & 255;
    int kh = rest >> 7, s = (rest >> 6) & 1, lane = rest & 63;
    int code = T * 16 + (lane & 15);
    const float* src = cb + (size_t)code * NDIM + kh * 128 + (lane >> 4) * 32 + s * 16;
    uint4 o;
    #pragma unroll
    for (int q = 0; q < 4; q++) {
        float4 v = *(const float4*)(src + q * 4);
        int r = __builtin_amdgcn_cvt_pk_fp8_f32(v.x * CBSCALE, v.y * CBSCALE, 0, false);
        r     = __builtin_amdgcn_cvt_pk_fp8_f32(v.z * CBSCALE, v.w * CBSCALE, r, true);
        ((u32*)&o)[q] = (u32)r;
    }
    *(uint4*)((char*)cbb8 + (size_t)u * 16) = o;
}

// ---------------- fully fused: GEMM + argmax + gather + ST + loss ----------------
// Block = 64 m-rows x ALL 8192 codes; grid 512 = 2 blocks/CU. Each of the 4
// waves holds ALL 64 rows in registers (A replicated) and owns a private
// codebook QUARTER (2048 codes = 128 16-code tiles) streamed from L2.
//
// R8 = R7 + PER-BLOCK TILE-RING ROTATION (anti-lockstep-hotspot).
// R7 accounting: 1539 cyc/phase/wave; matrix 552 (36% = MfmaUtil), VALU
// ~480 (29% = VALUBusy), ~500 cyc stalled at vmcnt. Aggregate L2 delivery
// only ~13 TB/s (vs 34.5 ceiling) at 21 B/cyc/CU demand -> loads are SLOW,
// not many. Cause: all 512 blocks run the identical instruction stream in
// lockstep, so at any instant wave w of EVERY block reads the SAME 4KB
// tile -> instantaneous hot footprint 16KB/2MB -> ~1/128 of L2/L3 banks
// active, 32 CUs/XCD queue on the same banks; queueing delay ~= 3 phases
// (Little: 96KB in flight / 21 B/cyc ~ 4500 cyc) = the observed wait age.
// Fix: block b processes its 128-tile ring starting at rotation
// rot = ((b>>3) + ((b&7)<<4)) & 127  -- all 64 co-XCD blocks get distinct
// rotations -> instantaneous footprint ~1MB/XCD -> all banks active.
// Argmax is order-invariant and keys carry absolute code ids, so any
// processing order is correct. (VGPR note: reported 108 excludes AGPRs;
// true unified usage ~190 -> occupancy is register-pinned at 2 waves/SIMD,
// so more TLP is unavailable; latency itself must drop.)
//
// Load pipeline unchanged from R6/R7: asm global_load_dwordx4 x4 with "=&v"
// early-clobber outputs, vmcnt(12) steady waits + sched_barrier(0) fences
// (rule #18), lag-1 argmax on two acc sets, peeled descending-wait tail,
// zero dead loads. acc-init eliminated via bias-C on the kh=0 MFMA.
__global__ __launch_bounds__(256, 2) void vq_fused_kernel(const float* __restrict__ z,
                                                          const float* __restrict__ cb,
                                                          const u32* __restrict__ cbb8,
                                                          float* __restrict__ out) {
    __shared__ u32 keys_lds[4][64];                  // [wave/quarter][row]
    __shared__ float red[4];

    int m0  = blockIdx.x * 64;
    int tid = threadIdx.x;
    int lane = tid & 63, w = tid >> 6;
    int qbase = w * (KCODES / 4);
    int l15 = lane & 15, quad = lane >> 4;
    int rot = (((int)blockIdx.x >> 3) + (((int)blockIdx.x & 7) << 4)) & 127;

    // ---- A prologue: ALL 64 block rows x 256 K fp32 -> fp8 in 64 VGPRs ----
    i32x8 A8[2][4];              // [kh(128-wide)][i-frag(16 rows)]
    #pragma unroll
    for (int kh = 0; kh < 2; kh++)
        #pragma unroll
        for (int i = 0; i < 4; i++) {
            const float* p = z + (size_t)(m0 + i * 16 + l15) * NDIM + kh * 128 + quad * 32;
            union { u32 u[8]; i32x8 v; } c;
            #pragma unroll
            for (int g = 0; g < 4; g++) {
                float4 x = *(const float4*)(p + g * 8);
                float4 y = *(const float4*)(p + g * 8 + 4);
                int r = __builtin_amdgcn_cvt_pk_fp8_f32(x.x, x.y, 0, false);
                r     = __builtin_amdgcn_cvt_pk_fp8_f32(x.z, x.w, r, true);
                c.u[g * 2] = (u32)r;
                r = __builtin_amdgcn_cvt_pk_fp8_f32(y.x, y.y, 0, false);
                r = __builtin_amdgcn_cvt_pk_fp8_f32(y.z, y.w, r, true);
                c.u[g * 2 + 1] = (u32)r;
            }
            A8[kh][i] = c.v;
        }
    // drain prologue loads so the raw vmcnt(N) below counts ONLY B-tile loads
    __asm__ volatile("s_waitcnt vmcnt(0)" ::: "memory");
    __builtin_amdgcn_sched_barrier(0);

    // ---- B stream: packed fragment layout, per-lane base + tile offsets ----
    // tile t of wave w lives at bytes (w*128 + t)*4096; lane slice = +lane*16.
    // pieces (kh,s) at byte offsets +0 / +1024 / +2048 / +3072.
    const char* lp = (const char*)cbb8 + (size_t)(w * 128) * 4096 + (size_t)lane * 16;

    auto loadt = [&](int4* b, int n) {
        int t = (n + rot) & 127;             // rotated ring position
        const char* pa = lp + (size_t)t * 4096;
        asm volatile("global_load_dwordx4 %0, %4, off\n\t"
                     "global_load_dwordx4 %1, %4, off offset:1024\n\t"
                     "global_load_dwordx4 %2, %4, off offset:2048\n\t"
                     "global_load_dwordx4 %3, %4, off offset:3072"
                     : "=&v"(b[0]), "=&v"(b[1]), "=&v"(b[2]), "=&v"(b[3])
                     : "v"(pa));
    };
    // buffer-resident waits; sched_barrier stops consumers hoisting (rule #18)
    auto wait12 = [&]() { asm volatile("s_waitcnt vmcnt(12)" ::: "memory");
                          __builtin_amdgcn_sched_barrier(0); };
    auto wait8  = [&]() { asm volatile("s_waitcnt vmcnt(8)"  ::: "memory");
                          __builtin_amdgcn_sched_barrier(0); };
    auto wait4  = [&]() { asm volatile("s_waitcnt vmcnt(4)"  ::: "memory");
                          __builtin_amdgcn_sched_barrier(0); };
    auto wait0  = [&]() { asm volatile("s_waitcnt vmcnt(0)"  ::: "memory");
                          __builtin_amdgcn_sched_barrier(0); };

    const f32x4 bias4 = {2048.f, 2048.f, 2048.f, 2048.f};
    float mkey[16];
    #pragma unroll
    for (int s = 0; s < 16; s++) mkey[s] = 0.f;

    // MFMA for one 16-code tile into the given acc set (no argmax here)
    auto domfma = [&](f32x4* acc, const int4* b) {
        union { int4 q[2]; i32x8 v; } u0, u1;
        u0.q[0] = b[0]; u0.q[1] = b[1];      // kh=0 fragment (32B/lane)
        u1.q[0] = b[2]; u1.q[1] = b[3];      // kh=1 fragment
        #pragma unroll
        for (int i = 0; i < 4; i++)
            acc[i] = __builtin_amdgcn_mfma_scale_f32_16x16x128_f8f6f4(
                         A8[0][i], u0.v, bias4, 0, 0, 0, 0x7F7F7F7F, 0, 0x7F7F7F7F);
        #pragma unroll
        for (int i = 0; i < 4; i++)
            acc[i] = __builtin_amdgcn_mfma_scale_f32_16x16x128_f8f6f4(
                         A8[1][i], u1.v, acc[i], 0, 0, 0, 0x7F7F7F7F, 0, 0x7F7F7F7F);
    };
    // packed-key argmax for a PREVIOUS tile (data ready a full phase ago)
    auto amax = [&](const f32x4* acc, int n) {
        int t = (n + rot) & 127;             // absolute tile id (rotated)
        int cb0 = qbase + t * 16 + l15;
        #pragma unroll
        for (int i = 0; i < 4; i++)
            #pragma unroll
            for (int r = 0; r < 4; r++) {
                u32 p = (__float_as_uint(acc[i][r]) & 0xFFFFE000u) | (u32)cb0;
                mkey[i * 4 + r] = fmaxf(mkey[i * 4 + r], __uint_as_float(p));
            }
    };

    // ---- main loop: 128 tiles, 4 forced reg buffers, 3-deep prefetch,
    //      lag-1 argmax on two acc sets (even tile -> accA, odd -> accB) ----
    f32x4 accA[4], accB[4];
    int4 bb0[4], bb1[4], bb2[4], bb3[4];
    loadt(bb0, 0); loadt(bb1, 1); loadt(bb2, 2);   // prime: 12 loads in flight

    // peeled first group: tiles 0..3 (tile 0 has no lag-1 argmax)
    loadt(bb3, 3);  wait12();  domfma(accA, bb0);
    loadt(bb0, 4);  wait12();  domfma(accB, bb1);  amax(accA, 0);
    loadt(bb1, 5);  wait12();  domfma(accA, bb2);  amax(accB, 1);
    loadt(bb2, 6);  wait12();  domfma(accB, bb3);  amax(accA, 2);

    #pragma unroll 1
    for (int n = 4; n < 124; n += 4) {
        loadt(bb3, n + 3);  wait12();  domfma(accA, bb0);  amax(accB, n - 1);
        loadt(bb0, n + 4);  wait12();  domfma(accB, bb1);  amax(accA, n);
        loadt(bb1, n + 5);  wait12();  domfma(accA, bb2);  amax(accB, n + 1);
        loadt(bb2, n + 6);  wait12();  domfma(accB, bb3);  amax(accA, n + 2);
    }
    // ---- peeled tail: tiles 124..127, descending waits, zero dead loads ----
    loadt(bb3, 127);
    wait12();  domfma(accA, bb0);  amax(accB, 123);
    wait8();   domfma(accB, bb1);  amax(accA, 124);
    wait4();   domfma(accA, bb2);  amax(accB, 125);
    wait0();   domfma(accB, bb3);  amax(accA, 126);
    amax(accB, 127);

    // ---- merge: reduce over 16 col-lanes, stash per-row keys in LDS ----
    #pragma unroll
    for (int s = 0; s < 16; s++) {
        float v = mkey[s];
        #pragma unroll
        for (int sh = 1; sh < 16; sh <<= 1)
            v = fmaxf(v, __shfl_xor(v, sh, 64));
        if (l15 == s)    // one writer per 16-lane group (4 quads -> 4 rows)
            keys_lds[w][(s >> 2) * 16 + quad * 4 + (s & 3)] = __float_as_uint(v);
    }
    __syncthreads();

    // ---- fused gather + straight-through + loss (block's own 64 rows) ----
    int d = lane * 4;
    float sacc = 0.f;
    #pragma unroll
    for (int g = 0; g < 16; g++) {
        int rl = w * 16 + g;
        u32 k0 = keys_lds[0][rl], k1 = keys_lds[1][rl];
        u32 k2 = keys_lds[2][rl], k3 = keys_lds[3][rl];
        u32 a = k0 > k1 ? k0 : k1;
        u32 b = k2 > k3 ? k2 : k3;
        u32 idx = (a > b ? a : b) & 0x1FFFu;
        size_t zoff = (size_t)(m0 + rl) * NDIM + d;
        float4 zv = *(const float4*)(z + zoff);
        float4 qv = *(const float4*)(cb + (size_t)idx * NDIM + d);
        float4 o;
        o.x = zv.x + (qv.x - zv.x);           // straight-through, matches ref fp ops
        o.y = zv.y + (qv.y - zv.y);
        o.z = zv.z + (qv.z - zv.z);
        o.w = zv.w + (qv.w - zv.w);
        *(float4*)(out + zoff) = o;
        float dx = zv.x - qv.x, dy = zv.y - qv.y, dz = zv.z - qv.z, dw = zv.w - qv.w;
        sacc += dx * dx + dy * dy + dz * dz + dw * dw;
    }
    #pragma unroll
    for (int off = 32; off > 0; off >>= 1) sacc += __shfl_down(sacc, off, 64);
    if (lane == 0) red[w] = sacc;
    __syncthreads();
    if (tid == 0) {
        float tot = (red[0] + red[1]) + (red[2] + red[3]);
        atomicAdd(out + ND_TOT, tot * (1.25f / 8388608.f));   // (0.25+1.0)*mean
    }
}

extern "C" void kernel_launch(void* const* d_in, const int* in_sizes, int n_in,
                              void* d_out, int out_size, void* d_ws, size_t ws_size,
                              hipStream_t stream) {
    const float* z  = (const float*)d_in[0];   // 8*256*64*64 fp32
    const float* cb = (const float*)d_in[1];   // 8192*256 fp32
    float* out = (float*)d_out;                // 8388608 quantized_st + 1 loss

    u32* cbb8 = (u32*)d_ws;                    // 2 MB (cb fp8, fragment-packed)

    prep_cb8_kernel<<<KCODES * NDIM / 16 / 256, 256, 0, stream>>>(cb, cbb8, out + ND_TOT);
    vq_fused_kernel<<<NROWS / 64, 256, 0, stream>>>(z, cb, cbb8, out);
}